// Round 13
// baseline (554.873 us; speedup 1.0000x reference)
//
#include <hip/hip_runtime.h>

#define NC 256
#define NB 32
#define HW4 1024
#define KC 768
#define BN_EPS 1e-5f
#define CG 16            // channels per apply slot

typedef float f32x4 __attribute__((ext_vector_type(4)));

__device__ __forceinline__ int spin_until(const int* p, int target) {
    for (long it = 0; it < 4000000L; ++it) {
        if (__hip_atomic_load(p, __ATOMIC_ACQUIRE, __HIP_MEMORY_SCOPE_AGENT) >= target)
            return 1;
        __builtin_amdgcn_s_sleep(32);
    }
    return 0;
}

// 2048 blocks = 32 batches x 64 slots, assigned by arrival-order tickets.
// Every slot: phase A = GAP over 4 planes. Then:
//   slots 32..34: filt rows k*256..k*256+255    (k = slot-32)
//   slots  0..31: apply CG=16 channels x half-plane (waits on filt)
//   slots 35..63: exit (free the CU slot for refill)
// Counter layout (ints): [0]=ticket; gapd[b]=ctrs[64+b*32] (max 1056);
// fild[b]=ctrs[2048+b*32] (max 3040). All < 4096 ints = 16384 B (memset'd).
__global__ __launch_bounds__(256) void mega_kernel(
    const float* __restrict__ x, const float* __restrict__ cw,
    const float* __restrict__ bn_w, const float* __restrict__ bn_b,
    const float* __restrict__ bn_m, const float* __restrict__ bn_v,
    const float* __restrict__ gamma, const float* __restrict__ beta,
    float* __restrict__ out, int* __restrict__ ctrs,
    float* __restrict__ g, float* __restrict__ f) {
    const int t = threadIdx.x;
    const int wave = t >> 6, lane = t & 63;

    __shared__ int s_ticket;
    __shared__ float red[4][4];
    __shared__ int ok_s;
    __shared__ float gs[NC];
    __shared__ float f_s[3][CG];
    __shared__ float ga_s[CG], be_s[CG];

    if (t == 0) s_ticket = atomicAdd(&ctrs[0], 1);
    __syncthreads();
    const int batch = s_ticket >> 6;
    const int slot  = s_ticket & 63;
    int* gapd = &ctrs[64 + batch * 32];
    int* fild = &ctrs[2048 + batch * 32];

    const f32x4* x4 = reinterpret_cast<const f32x4*>(x);
    const size_t bbase = (size_t)batch * NC * HW4;

    // ---------------- Phase A: GAP over 4 planes ----------------
    {
        const int cA = slot * 4;
        const f32x4* xp = x4 + bbase + (size_t)cA * HW4;
        float s[4];
#pragma unroll
        for (int p = 0; p < 4; ++p) {
            f32x4 a = xp[(size_t)p * HW4 + t];
            f32x4 b = xp[(size_t)p * HW4 + t + 256];
            f32x4 c = xp[(size_t)p * HW4 + t + 512];
            f32x4 d = xp[(size_t)p * HW4 + t + 768];
            s[p] = (((a.x + a.y) + (a.z + a.w)) + ((b.x + b.y) + (b.z + b.w))) +
                   (((c.x + c.y) + (c.z + c.w)) + ((d.x + d.y) + (d.z + d.w)));
        }
#pragma unroll
        for (int p = 0; p < 4; ++p) {
            float v = s[p];
#pragma unroll
            for (int off = 32; off > 0; off >>= 1) v += __shfl_down(v, off, 64);
            if (lane == 0) red[wave][p] = v;
        }
        __syncthreads();
        if (t < 4) {
            float tot = (red[0][t] + red[1][t]) + (red[2][t] + red[3][t]);
            g[batch * NC + cA + t] = tot * (1.0f / 4096.0f);
        }
        __threadfence();
        __syncthreads();
        if (t == 0) atomicAdd(gapd, 1);
    }

    if (slot >= 35) return;

    if (slot >= 32) {
        // ---------------- FILT: rows k*256 .. k*256+255 ----------------
        const int k = slot - 32;
        if (t == 0) ok_s = spin_until(gapd, 64);
        __syncthreads();
        if (!ok_s) return;
        gs[t] = __hip_atomic_load(&g[batch * NC + t], __ATOMIC_RELAXED,
                                  __HIP_MEMORY_SCOPE_AGENT);
        __syncthreads();
        const int j = k * NC + t;
        const f32x4* wr = reinterpret_cast<const f32x4*>(cw + (size_t)j * NC);
        const f32x4* g4 = reinterpret_cast<const f32x4*>(gs);
        float a0 = 0.f, a1 = 0.f, a2 = 0.f, a3 = 0.f;
#pragma unroll 8
        for (int c = 0; c < 64; ++c) {
            const f32x4 wv = wr[c];
            const f32x4 gv = g4[c];
            a0 = fmaf(gv.x, wv.x, a0);
            a1 = fmaf(gv.y, wv.y, a1);
            a2 = fmaf(gv.z, wv.z, a2);
            a3 = fmaf(gv.w, wv.w, a3);
        }
        const float acc = (a0 + a1) + (a2 + a3);
        const float yn = (acc - bn_m[j]) * rsqrtf(bn_v[j] + BN_EPS) * bn_w[j] + bn_b[j];
        f[batch * KC + j] = tanhf(yn);
        __threadfence();
        __syncthreads();
        if (t == 0) atomicAdd(fild, 1);
        return;
    }

    // ---------------- APPLY: CG=16 channels x half-plane ----------------
    {
        const int chgrp = slot >> 1;
        const int half  = slot & 1;
        const int c0    = chgrp * CG;
        if (t == 0) ok_s = spin_until(fild, 3);
        __syncthreads();
        if (!ok_s) return;
        if (t < 48)
            f_s[t >> 4][t & 15] = __hip_atomic_load(
                &f[batch * KC + (t >> 4) * NC + c0 + (t & 15)],
                __ATOMIC_RELAXED, __HIP_MEMORY_SCOPE_AGENT);
        else if (t >= 64 && t < 80) ga_s[t - 64] = gamma[c0 + t - 64];
        else if (t >= 80 && t < 96) be_s[t - 80] = beta[c0 + t - 80];
        __syncthreads();

        f32x4* o4 = reinterpret_cast<f32x4*>(out);
        const int col0 = half * 512 + t;
        const int col1 = col0 + 256;
        const f32x4* xb = x4 + bbase;
        f32x4* ob = o4 + bbase;

        f32x4 cur0 = xb[(size_t)c0 * HW4 + col0];
        f32x4 cur1 = xb[(size_t)c0 * HW4 + col1];
        f32x4 nxt0 = xb[(size_t)(c0 + 1) * HW4 + col0];
        f32x4 nxt1 = xb[(size_t)(c0 + 1) * HW4 + col1];
        f32x4 prv0, prv1;
        if (c0 == 0) { prv0 = nxt0; prv1 = nxt1; }
        else {
            prv0 = xb[(size_t)(c0 - 1) * HW4 + col0];
            prv1 = xb[(size_t)(c0 - 1) * HW4 + col1];
        }

#pragma unroll 4
        for (int ci = 0; ci < CG; ++ci) {
            const int c  = c0 + ci;
            const int cn = (c + 2 < NC) ? (c + 2) : (NC - 1);
            f32x4 nn0 = xb[(size_t)cn * HW4 + col0];
            f32x4 nn1 = xb[(size_t)cn * HW4 + col1];
            const float f0 = f_s[0][ci];
            const float f1 = f_s[1][ci];
            const float f2 = f_s[2][ci];
            const float ga = ga_s[ci];
            const float be = be_s[ci];
            const f32x4 xm0 = (c == 0) ? nxt0 : prv0;        // reflect left
            const f32x4 xm1 = (c == 0) ? nxt1 : prv1;
            const f32x4 xq0 = (c == NC - 1) ? prv0 : nxt0;   // reflect right
            const f32x4 xq1 = (c == NC - 1) ? prv1 : nxt1;
            f32x4 r0, r1;
            r0.x = fmaf(fmaf(f0, xm0.x, fmaf(f1, cur0.x, f2 * xq0.x)), ga, cur0.x * be);
            r0.y = fmaf(fmaf(f0, xm0.y, fmaf(f1, cur0.y, f2 * xq0.y)), ga, cur0.y * be);
            r0.z = fmaf(fmaf(f0, xm0.z, fmaf(f1, cur0.z, f2 * xq0.z)), ga, cur0.z * be);
            r0.w = fmaf(fmaf(f0, xm0.w, fmaf(f1, cur0.w, f2 * xq0.w)), ga, cur0.w * be);
            r1.x = fmaf(fmaf(f0, xm1.x, fmaf(f1, cur1.x, f2 * xq1.x)), ga, cur1.x * be);
            r1.y = fmaf(fmaf(f0, xm1.y, fmaf(f1, cur1.y, f2 * xq1.y)), ga, cur1.y * be);
            r1.z = fmaf(fmaf(f0, xm1.z, fmaf(f1, cur1.z, f2 * xq1.z)), ga, cur1.z * be);
            r1.w = fmaf(fmaf(f0, xm1.w, fmaf(f1, cur1.w, f2 * xq1.w)), ga, cur1.w * be);
            ob[(size_t)c * HW4 + col0] = r0;
            ob[(size_t)c * HW4 + col1] = r1;
            prv0 = cur0; cur0 = nxt0; nxt0 = nn0;
            prv1 = cur1; cur1 = nxt1; nxt1 = nn1;
        }
    }
}

extern "C" void kernel_launch(void* const* d_in, const int* in_sizes, int n_in,
                              void* d_out, int out_size, void* d_ws, size_t ws_size,
                              hipStream_t stream) {
    const float* x     = (const float*)d_in[0];
    const float* cw    = (const float*)d_in[1];
    const float* bn_w  = (const float*)d_in[2];
    const float* bn_b  = (const float*)d_in[3];
    const float* bn_m  = (const float*)d_in[4];
    const float* bn_v  = (const float*)d_in[5];
    const float* gamma = (const float*)d_in[6];
    const float* beta  = (const float*)d_in[7];
    float* out = (float*)d_out;

    int*   ctrs = (int*)d_ws;                                   // 16 KB counters
    float* g    = (float*)((char*)d_ws + 16384);                // 32 KB
    float* f    = (float*)((char*)d_ws + 16384 + 32768);        // 96 KB

    hipMemsetAsync(d_ws, 0, 16384, stream);
    mega_kernel<<<NB * 64, 256, 0, stream>>>(
        x, cw, bn_w, bn_b, bn_m, bn_v, gamma, beta, out, ctrs, g, f);
}

// Round 14
// 396.156 us; speedup vs baseline: 1.4006x; 1.4006x over previous
//
#include <hip/hip_runtime.h>

#define NC 256
#define NB 32
#define HW4 1024
#define KC 768
#define BN_EPS 1e-5f
#define CG 16            // channels per apply slot

typedef float f32x4 __attribute__((ext_vector_type(4)));

__device__ __forceinline__ int spin_until(const int* p, int target) {
    // RELAXED polls (no per-poll L2 invalidate); one ACQUIRE on success to
    // order subsequent data reads. R13's acquire-per-poll caused an
    // invalidate storm that throttled HBM to 400 GB/s machine-wide.
    for (long it = 0; it < 4000000L; ++it) {
        if (__hip_atomic_load(p, __ATOMIC_RELAXED, __HIP_MEMORY_SCOPE_AGENT) >= target) {
            (void)__hip_atomic_load(p, __ATOMIC_ACQUIRE, __HIP_MEMORY_SCOPE_AGENT);
            return 1;
        }
        __builtin_amdgcn_s_sleep(32);
    }
    return 0;
}

// 2048 blocks = 32 batches x 64 slots, assigned by arrival-order tickets.
// Every slot: phase A = GAP over 4 planes. Then:
//   slots 32..34: filt rows k*256..k*256+255    (k = slot-32)
//   slots  0..31: apply CG=16 channels x half-plane (waits on filt)
//   slots 35..63: exit (free the CU slot for refill)
// Counter layout (ints): [0]=ticket; gapd[b]=ctrs[64+b*32] (max 1056);
// fild[b]=ctrs[2048+b*32] (max 3040). All < 4096 ints = 16384 B (memset'd).
__global__ __launch_bounds__(256) void mega_kernel(
    const float* __restrict__ x, const float* __restrict__ cw,
    const float* __restrict__ bn_w, const float* __restrict__ bn_b,
    const float* __restrict__ bn_m, const float* __restrict__ bn_v,
    const float* __restrict__ gamma, const float* __restrict__ beta,
    float* __restrict__ out, int* __restrict__ ctrs,
    float* __restrict__ g, float* __restrict__ f) {
    const int t = threadIdx.x;
    const int wave = t >> 6, lane = t & 63;

    __shared__ int s_ticket;
    __shared__ float red[4][4];
    __shared__ int ok_s;
    __shared__ float gs[NC];
    __shared__ float f_s[3][CG];
    __shared__ float ga_s[CG], be_s[CG];

    if (t == 0) s_ticket = atomicAdd(&ctrs[0], 1);
    __syncthreads();
    const int batch = s_ticket >> 6;
    const int slot  = s_ticket & 63;
    int* gapd = &ctrs[64 + batch * 32];
    int* fild = &ctrs[2048 + batch * 32];

    const f32x4* x4 = reinterpret_cast<const f32x4*>(x);
    const size_t bbase = (size_t)batch * NC * HW4;

    // ---------------- Phase A: GAP over 4 planes ----------------
    {
        const int cA = slot * 4;
        const f32x4* xp = x4 + bbase + (size_t)cA * HW4;
        float s[4];
#pragma unroll
        for (int p = 0; p < 4; ++p) {
            f32x4 a = xp[(size_t)p * HW4 + t];
            f32x4 b = xp[(size_t)p * HW4 + t + 256];
            f32x4 c = xp[(size_t)p * HW4 + t + 512];
            f32x4 d = xp[(size_t)p * HW4 + t + 768];
            s[p] = (((a.x + a.y) + (a.z + a.w)) + ((b.x + b.y) + (b.z + b.w))) +
                   (((c.x + c.y) + (c.z + c.w)) + ((d.x + d.y) + (d.z + d.w)));
        }
#pragma unroll
        for (int p = 0; p < 4; ++p) {
            float v = s[p];
#pragma unroll
            for (int off = 32; off > 0; off >>= 1) v += __shfl_down(v, off, 64);
            if (lane == 0) red[wave][p] = v;
        }
        __syncthreads();
        if (t < 4) {
            float tot = (red[0][t] + red[1][t]) + (red[2][t] + red[3][t]);
            g[batch * NC + cA + t] = tot * (1.0f / 4096.0f);
        }
        __threadfence();
        __syncthreads();
        if (t == 0) atomicAdd(gapd, 1);
    }

    if (slot >= 35) return;

    if (slot >= 32) {
        // ---------------- FILT: rows k*256 .. k*256+255 ----------------
        const int k = slot - 32;
        if (t == 0) ok_s = spin_until(gapd, 64);
        __syncthreads();
        if (!ok_s) return;
        gs[t] = __hip_atomic_load(&g[batch * NC + t], __ATOMIC_RELAXED,
                                  __HIP_MEMORY_SCOPE_AGENT);
        __syncthreads();
        const int j = k * NC + t;
        const f32x4* wr = reinterpret_cast<const f32x4*>(cw + (size_t)j * NC);
        const f32x4* g4 = reinterpret_cast<const f32x4*>(gs);
        float a0 = 0.f, a1 = 0.f, a2 = 0.f, a3 = 0.f;
#pragma unroll 8
        for (int c = 0; c < 64; ++c) {
            const f32x4 wv = wr[c];
            const f32x4 gv = g4[c];
            a0 = fmaf(gv.x, wv.x, a0);
            a1 = fmaf(gv.y, wv.y, a1);
            a2 = fmaf(gv.z, wv.z, a2);
            a3 = fmaf(gv.w, wv.w, a3);
        }
        const float acc = (a0 + a1) + (a2 + a3);
        const float yn = (acc - bn_m[j]) * rsqrtf(bn_v[j] + BN_EPS) * bn_w[j] + bn_b[j];
        f[batch * KC + j] = tanhf(yn);
        __threadfence();
        __syncthreads();
        if (t == 0) atomicAdd(fild, 1);
        return;
    }

    // ---------------- APPLY: CG=16 channels x half-plane ----------------
    {
        const int chgrp = slot >> 1;
        const int half  = slot & 1;
        const int c0    = chgrp * CG;
        if (t == 0) ok_s = spin_until(fild, 3);
        __syncthreads();
        if (!ok_s) return;
        if (t < 48)
            f_s[t >> 4][t & 15] = __hip_atomic_load(
                &f[batch * KC + (t >> 4) * NC + c0 + (t & 15)],
                __ATOMIC_RELAXED, __HIP_MEMORY_SCOPE_AGENT);
        else if (t >= 64 && t < 80) ga_s[t - 64] = gamma[c0 + t - 64];
        else if (t >= 80 && t < 96) be_s[t - 80] = beta[c0 + t - 80];
        __syncthreads();

        f32x4* o4 = reinterpret_cast<f32x4*>(out);
        const int col0 = half * 512 + t;
        const int col1 = col0 + 256;
        const f32x4* xb = x4 + bbase;
        f32x4* ob = o4 + bbase;

        f32x4 cur0 = xb[(size_t)c0 * HW4 + col0];
        f32x4 cur1 = xb[(size_t)c0 * HW4 + col1];
        f32x4 nxt0 = xb[(size_t)(c0 + 1) * HW4 + col0];
        f32x4 nxt1 = xb[(size_t)(c0 + 1) * HW4 + col1];
        f32x4 prv0, prv1;
        if (c0 == 0) { prv0 = nxt0; prv1 = nxt1; }
        else {
            prv0 = xb[(size_t)(c0 - 1) * HW4 + col0];
            prv1 = xb[(size_t)(c0 - 1) * HW4 + col1];
        }

#pragma unroll 4
        for (int ci = 0; ci < CG; ++ci) {
            const int c  = c0 + ci;
            const int cn = (c + 2 < NC) ? (c + 2) : (NC - 1);
            f32x4 nn0 = xb[(size_t)cn * HW4 + col0];
            f32x4 nn1 = xb[(size_t)cn * HW4 + col1];
            const float f0 = f_s[0][ci];
            const float f1 = f_s[1][ci];
            const float f2 = f_s[2][ci];
            const float ga = ga_s[ci];
            const float be = be_s[ci];
            const f32x4 xm0 = (c == 0) ? nxt0 : prv0;        // reflect left
            const f32x4 xm1 = (c == 0) ? nxt1 : prv1;
            const f32x4 xq0 = (c == NC - 1) ? prv0 : nxt0;   // reflect right
            const f32x4 xq1 = (c == NC - 1) ? prv1 : nxt1;
            f32x4 r0, r1;
            r0.x = fmaf(fmaf(f0, xm0.x, fmaf(f1, cur0.x, f2 * xq0.x)), ga, cur0.x * be);
            r0.y = fmaf(fmaf(f0, xm0.y, fmaf(f1, cur0.y, f2 * xq0.y)), ga, cur0.y * be);
            r0.z = fmaf(fmaf(f0, xm0.z, fmaf(f1, cur0.z, f2 * xq0.z)), ga, cur0.z * be);
            r0.w = fmaf(fmaf(f0, xm0.w, fmaf(f1, cur0.w, f2 * xq0.w)), ga, cur0.w * be);
            r1.x = fmaf(fmaf(f0, xm1.x, fmaf(f1, cur1.x, f2 * xq1.x)), ga, cur1.x * be);
            r1.y = fmaf(fmaf(f0, xm1.y, fmaf(f1, cur1.y, f2 * xq1.y)), ga, cur1.y * be);
            r1.z = fmaf(fmaf(f0, xm1.z, fmaf(f1, cur1.z, f2 * xq1.z)), ga, cur1.z * be);
            r1.w = fmaf(fmaf(f0, xm1.w, fmaf(f1, cur1.w, f2 * xq1.w)), ga, cur1.w * be);
            ob[(size_t)c * HW4 + col0] = r0;
            ob[(size_t)c * HW4 + col1] = r1;
            prv0 = cur0; cur0 = nxt0; nxt0 = nn0;
            prv1 = cur1; cur1 = nxt1; nxt1 = nn1;
        }
    }
}

extern "C" void kernel_launch(void* const* d_in, const int* in_sizes, int n_in,
                              void* d_out, int out_size, void* d_ws, size_t ws_size,
                              hipStream_t stream) {
    const float* x     = (const float*)d_in[0];
    const float* cw    = (const float*)d_in[1];
    const float* bn_w  = (const float*)d_in[2];
    const float* bn_b  = (const float*)d_in[3];
    const float* bn_m  = (const float*)d_in[4];
    const float* bn_v  = (const float*)d_in[5];
    const float* gamma = (const float*)d_in[6];
    const float* beta  = (const float*)d_in[7];
    float* out = (float*)d_out;

    int*   ctrs = (int*)d_ws;                                   // 16 KB counters
    float* g    = (float*)((char*)d_ws + 16384);                // 32 KB
    float* f    = (float*)((char*)d_ws + 16384 + 32768);        // 96 KB

    hipMemsetAsync(d_ws, 0, 16384, stream);
    mega_kernel<<<NB * 64, 256, 0, stream>>>(
        x, cw, bn_w, bn_b, bn_m, bn_v, gamma, beta, out, ctrs, g, f);
}

// Round 15
// 114.580 us; speedup vs baseline: 4.8427x; 3.4575x over previous
//
#include <hip/hip_runtime.h>

#define NC 256
#define NB 32
#define HW4 1024
#define KC 768
#define BN_EPS 1e-5f

typedef float f32x4 __attribute__((ext_vector_type(4)));

__device__ __forceinline__ int spin_until(const int* p, int target) {
    for (long it = 0; it < 4000000L; ++it) {
        if (__hip_atomic_load(p, __ATOMIC_RELAXED, __HIP_MEMORY_SCOPE_AGENT) >= target) {
            (void)__hip_atomic_load(p, __ATOMIC_ACQUIRE, __HIP_MEMORY_SCOPE_AGENT);
            return 1;
        }
        __builtin_amdgcn_s_sleep(8);
    }
    return 0;
}

// 256 blocks = 32 batches x 8 slots, 1 block/CU, ALL co-resident by capacity
// (no tickets, no cooperative launch). Every block: GAP over its 32 channels ->
// one 8-way sync -> local taps (no exchange) -> apply its 32 channels.
__global__ __launch_bounds__(256) void mega_kernel(
    const float* __restrict__ x, const float* __restrict__ cw,
    const float* __restrict__ bn_w, const float* __restrict__ bn_b,
    const float* __restrict__ bn_m, const float* __restrict__ bn_v,
    const float* __restrict__ gamma, const float* __restrict__ beta,
    float* __restrict__ out, int* __restrict__ ctrs, float* __restrict__ g) {
    const int bid   = blockIdx.x;     // 256
    const int batch = bid >> 3;
    const int slot  = bid & 7;
    const int c0    = slot * 32;
    const int t     = threadIdx.x;
    const int wave  = t >> 6, lane = t & 63;

    __shared__ float red[4][8];
    __shared__ int ok_s;
    __shared__ float gs[NC];
    __shared__ float f_s[3][32];
    __shared__ float ga_s[32], be_s[32];

    int* gapd = &ctrs[batch * 32];    // one 128B line per batch
    const f32x4* x4 = reinterpret_cast<const f32x4*>(x);
    const size_t bbase = (size_t)batch * NC * HW4;

    // ---------------- Phase A: GAP over 32 planes (8 per barrier group) ----------------
    {
        const f32x4* xp = x4 + bbase + (size_t)c0 * HW4;
        for (int p0 = 0; p0 < 32; p0 += 8) {
            float s[8];
#pragma unroll
            for (int p = 0; p < 8; ++p) {
                const size_t pb = (size_t)(p0 + p) * HW4;
                f32x4 a = xp[pb + t];
                f32x4 b = xp[pb + t + 256];
                f32x4 c = xp[pb + t + 512];
                f32x4 d = xp[pb + t + 768];
                s[p] = (((a.x + a.y) + (a.z + a.w)) + ((b.x + b.y) + (b.z + b.w))) +
                       (((c.x + c.y) + (c.z + c.w)) + ((d.x + d.y) + (d.z + d.w)));
            }
#pragma unroll
            for (int p = 0; p < 8; ++p) {
                float v = s[p];
#pragma unroll
                for (int off = 32; off > 0; off >>= 1) v += __shfl_down(v, off, 64);
                if (lane == 0) red[wave][p] = v;
            }
            __syncthreads();
            if (t < 8) {
                float tot = (red[0][t] + red[1][t]) + (red[2][t] + red[3][t]);
                g[batch * NC + c0 + p0 + t] = tot * (1.0f / 4096.0f);
            }
            __syncthreads();
        }
        __threadfence();
        __syncthreads();
        if (t == 0) atomicAdd(gapd, 1);
    }

    // ---------------- Sync: wait for the 7 sibling blocks ----------------
    if (t == 0) ok_s = spin_until(gapd, 8);
    __syncthreads();
    if (!ok_s) return;
    gs[t] = __hip_atomic_load(&g[batch * NC + t], __ATOMIC_RELAXED,
                              __HIP_MEMORY_SCOPE_AGENT);
    // stage gamma/beta meanwhile
    if (t >= 192 && t < 224) ga_s[t - 192] = gamma[c0 + t - 192];
    else if (t >= 224)       be_s[t - 224] = beta[c0 + t - 224];
    __syncthreads();

    // ---------------- Phase B: 96 local taps (24 rows/wave), no exchange ----------------
    {
        const f32x4 gv = reinterpret_cast<const f32x4*>(gs)[lane];
#pragma unroll 4
        for (int r = 0; r < 24; ++r) {
            const int rl = wave * 24 + r;          // 0..95
            const int k  = rl >> 5;
            const int ci = rl & 31;
            const int j  = k * NC + c0 + ci;
            const f32x4 wv = reinterpret_cast<const f32x4*>(cw + (size_t)j * NC)[lane];
            float s = fmaf(gv.x, wv.x, fmaf(gv.y, wv.y, fmaf(gv.z, wv.z, gv.w * wv.w)));
#pragma unroll
            for (int off = 32; off > 0; off >>= 1) s += __shfl_down(s, off, 64);
            if (lane == 0) {
                const float yn = (s - bn_m[j]) * rsqrtf(bn_v[j] + BN_EPS) * bn_w[j] + bn_b[j];
                f_s[k][ci] = tanhf(yn);
            }
        }
    }
    __syncthreads();

    // ---------------- Phase C: apply 32 channels x full plane (R8 structure) ----------------
    {
        const f32x4* xb = x4 + bbase;
        f32x4* ob = reinterpret_cast<f32x4*>(out) + bbase;

        f32x4 prv[4], cur[4], nxt[4];
#pragma unroll
        for (int j = 0; j < 4; ++j) cur[j] = xb[(size_t)c0 * HW4 + t + j * 256];
#pragma unroll
        for (int j = 0; j < 4; ++j) nxt[j] = xb[(size_t)(c0 + 1) * HW4 + t + j * 256];
        if (c0 == 0) {
#pragma unroll
            for (int j = 0; j < 4; ++j) prv[j] = nxt[j];
        } else {
#pragma unroll
            for (int j = 0; j < 4; ++j) prv[j] = xb[(size_t)(c0 - 1) * HW4 + t + j * 256];
        }

#pragma unroll 2
        for (int ci = 0; ci < 32; ++ci) {
            const int c  = c0 + ci;
            const int cn = (c + 2 < NC) ? (c + 2) : (NC - 1);
            f32x4 nn[4];
#pragma unroll
            for (int j = 0; j < 4; ++j) nn[j] = xb[(size_t)cn * HW4 + t + j * 256];
            const float f0 = f_s[0][ci];
            const float f1 = f_s[1][ci];
            const float f2 = f_s[2][ci];
            const float ga = ga_s[ci];
            const float be = be_s[ci];
#pragma unroll
            for (int j = 0; j < 4; ++j) {
                const f32x4 xm = (c == 0) ? nxt[j] : prv[j];        // reflect left
                const f32x4 xq = (c == NC - 1) ? prv[j] : nxt[j];   // reflect right
                const f32x4 xc = cur[j];
                f32x4 r;
                r.x = fmaf(fmaf(f0, xm.x, fmaf(f1, xc.x, f2 * xq.x)), ga, xc.x * be);
                r.y = fmaf(fmaf(f0, xm.y, fmaf(f1, xc.y, f2 * xq.y)), ga, xc.y * be);
                r.z = fmaf(fmaf(f0, xm.z, fmaf(f1, xc.z, f2 * xq.z)), ga, xc.z * be);
                r.w = fmaf(fmaf(f0, xm.w, fmaf(f1, xc.w, f2 * xq.w)), ga, xc.w * be);
                ob[(size_t)c * HW4 + t + j * 256] = r;
            }
#pragma unroll
            for (int j = 0; j < 4; ++j) { prv[j] = cur[j]; cur[j] = nxt[j]; nxt[j] = nn[j]; }
        }
    }
}

extern "C" void kernel_launch(void* const* d_in, const int* in_sizes, int n_in,
                              void* d_out, int out_size, void* d_ws, size_t ws_size,
                              hipStream_t stream) {
    const float* x     = (const float*)d_in[0];
    const float* cw    = (const float*)d_in[1];
    const float* bn_w  = (const float*)d_in[2];
    const float* bn_b  = (const float*)d_in[3];
    const float* bn_m  = (const float*)d_in[4];
    const float* bn_v  = (const float*)d_in[5];
    const float* gamma = (const float*)d_in[6];
    const float* beta  = (const float*)d_in[7];
    float* out = (float*)d_out;

    int*   ctrs = (int*)d_ws;                        // 8 KB counters (32*32 ints used)
    float* g    = (float*)((char*)d_ws + 8192);      // 32 KB

    hipMemsetAsync(d_ws, 0, 8192, stream);
    mega_kernel<<<256, 256, 0, stream>>>(
        x, cw, bn_w, bn_b, bn_m, bn_v, gamma, beta, out, ctrs, g);
}

// Round 16
// 73.275 us; speedup vs baseline: 7.5725x; 1.5637x over previous
//
#include <hip/hip_runtime.h>

#define NC 256
#define NB 32
#define HW 4096
#define HW4 1024
#define KC 768   // KERNEL * NC
#define BN_EPS 1e-5f
#define CG 64    // channels per apply block

typedef float f32x4 __attribute__((ext_vector_type(4)));

// ---------------- Kernel 1: global average pool per (b,c) ----------------
__global__ __launch_bounds__(256) void gap_kernel(const float* __restrict__ x,
                                                  float* __restrict__ g) {
    const int bc = blockIdx.x;
    const f32x4* xp = reinterpret_cast<const f32x4*>(x) + (size_t)bc * HW4;
    const int t = threadIdx.x;
    float s = 0.f;
#pragma unroll
    for (int k = 0; k < 4; ++k) {
        f32x4 v = xp[t + k * 256];
        s += (v.x + v.y) + (v.z + v.w);
    }
#pragma unroll
    for (int off = 32; off > 0; off >>= 1) s += __shfl_down(s, off, 64);
    __shared__ float warp_sums[4];
    const int lane = t & 63, w = t >> 6;
    if (lane == 0) warp_sums[w] = s;
    __syncthreads();
    if (t == 0) {
        float tot = (warp_sums[0] + warp_sums[1]) + (warp_sums[2] + warp_sums[3]);
        g[bc] = tot * (1.0f / HW);
    }
}

// ---------------- Kernel 2: 1x1 conv (768x256 dot) + BN + tanh ----------------
__global__ __launch_bounds__(256) void filt_kernel(const float* __restrict__ g,
                                                   const float* __restrict__ cw,
                                                   const float* __restrict__ bn_w,
                                                   const float* __restrict__ bn_b,
                                                   const float* __restrict__ bn_m,
                                                   const float* __restrict__ bn_v,
                                                   float* __restrict__ f) {
    const int b = blockIdx.y;
    const int t = threadIdx.x;
    __shared__ float gs[NC];
    gs[t] = g[b * NC + t];
    __syncthreads();
    const int wave = t >> 6, lane = t & 63;
    const f32x4 gv = reinterpret_cast<const f32x4*>(gs)[lane];
    const int row0 = blockIdx.x * 32 + wave * 8;
#pragma unroll
    for (int i = 0; i < 8; ++i) {
        const int j = row0 + i;
        const f32x4 wv = reinterpret_cast<const f32x4*>(cw + (size_t)j * NC)[lane];
        float s = fmaf(gv.x, wv.x, fmaf(gv.y, wv.y, fmaf(gv.z, wv.z, gv.w * wv.w)));
#pragma unroll
        for (int off = 32; off > 0; off >>= 1) s += __shfl_down(s, off, 64);
        if (lane == 0) {
            float yn = (s - bn_m[j]) * rsqrtf(bn_v[j] + BN_EPS) * bn_w[j] + bn_b[j];
            f[b * KC + j] = tanhf(yn);
        }
    }
}

// ---------------- Kernel 3: dynamic channel-local filter + affine ----------------
// 256 blocks: (b, 64-ch group, plane-half). 2 f32x4 columns/thread -> 8KB-linear
// streams; halo 2/64 = 3.1%; depth-2 prefetch (5-plane window, ~40 VGPRs).
__global__ __launch_bounds__(256) void apply_kernel(const float* __restrict__ x,
                                                    const float* __restrict__ f,
                                                    const float* __restrict__ gamma,
                                                    const float* __restrict__ beta,
                                                    float* __restrict__ out) {
    const int bid  = blockIdx.x;        // 256
    const int half = bid & 1;
    const int cgp  = (bid >> 1) & 3;
    const int b    = bid >> 3;
    const int t    = threadIdx.x;
    const int c0   = cgp * CG;

    __shared__ float f_s[3][CG];
    __shared__ float ga_s[CG], be_s[CG];
    {
        const float* fb = f + b * KC;
        if (t < 192)      f_s[t >> 6][t & 63] = fb[(t >> 6) * NC + c0 + (t & 63)];
        else              ga_s[t - 192] = gamma[c0 + t - 192];
        if (t < CG)       be_s[t] = beta[c0 + t];
    }

    const size_t bbase = (size_t)b * NC * HW4;
    const f32x4* x4 = reinterpret_cast<const f32x4*>(x) + bbase;
    f32x4* o4 = reinterpret_cast<f32x4*>(out) + bbase;
    const int col0 = half * 512 + t;
    const int col1 = col0 + 256;

    // 5-plane pipeline per column: prv,cur,nxt active; p2,p3 in flight
    f32x4 cur0 = x4[(size_t)c0 * HW4 + col0];
    f32x4 cur1 = x4[(size_t)c0 * HW4 + col1];
    f32x4 nxt0 = x4[(size_t)(c0 + 1) * HW4 + col0];
    f32x4 nxt1 = x4[(size_t)(c0 + 1) * HW4 + col1];
    f32x4 p20  = x4[(size_t)(c0 + 2) * HW4 + col0];
    f32x4 p21  = x4[(size_t)(c0 + 2) * HW4 + col1];
    f32x4 p30  = x4[(size_t)(c0 + 3) * HW4 + col0];
    f32x4 p31  = x4[(size_t)(c0 + 3) * HW4 + col1];
    f32x4 prv0, prv1;
    if (c0 == 0) { prv0 = nxt0; prv1 = nxt1; }
    else {
        prv0 = x4[(size_t)(c0 - 1) * HW4 + col0];
        prv1 = x4[(size_t)(c0 - 1) * HW4 + col1];
    }
    __syncthreads();

#pragma unroll 4
    for (int ci = 0; ci < CG; ++ci) {
        const int c  = c0 + ci;
        const int cn = (c + 4 < NC) ? (c + 4) : (NC - 1);   // clamped prefetch
        f32x4 nn0 = x4[(size_t)cn * HW4 + col0];
        f32x4 nn1 = x4[(size_t)cn * HW4 + col1];
        const float f0 = f_s[0][ci];
        const float f1 = f_s[1][ci];
        const float f2 = f_s[2][ci];
        const float ga = ga_s[ci];
        const float be = be_s[ci];
        const f32x4 xm0 = (c == 0) ? nxt0 : prv0;        // reflect left
        const f32x4 xm1 = (c == 0) ? nxt1 : prv1;
        const f32x4 xq0 = (c == NC - 1) ? prv0 : nxt0;   // reflect right
        const f32x4 xq1 = (c == NC - 1) ? prv1 : nxt1;
        f32x4 r0, r1;
        r0.x = fmaf(fmaf(f0, xm0.x, fmaf(f1, cur0.x, f2 * xq0.x)), ga, cur0.x * be);
        r0.y = fmaf(fmaf(f0, xm0.y, fmaf(f1, cur0.y, f2 * xq0.y)), ga, cur0.y * be);
        r0.z = fmaf(fmaf(f0, xm0.z, fmaf(f1, cur0.z, f2 * xq0.z)), ga, cur0.z * be);
        r0.w = fmaf(fmaf(f0, xm0.w, fmaf(f1, cur0.w, f2 * xq0.w)), ga, cur0.w * be);
        r1.x = fmaf(fmaf(f0, xm1.x, fmaf(f1, cur1.x, f2 * xq1.x)), ga, cur1.x * be);
        r1.y = fmaf(fmaf(f0, xm1.y, fmaf(f1, cur1.y, f2 * xq1.y)), ga, cur1.y * be);
        r1.z = fmaf(fmaf(f0, xm1.z, fmaf(f1, cur1.z, f2 * xq1.z)), ga, cur1.z * be);
        r1.w = fmaf(fmaf(f0, xm1.w, fmaf(f1, cur1.w, f2 * xq1.w)), ga, cur1.w * be);
        o4[(size_t)c * HW4 + col0] = r0;
        o4[(size_t)c * HW4 + col1] = r1;
        prv0 = cur0; cur0 = nxt0; nxt0 = p20; p20 = p30; p30 = nn0;
        prv1 = cur1; cur1 = nxt1; nxt1 = p21; p21 = p31; p31 = nn1;
    }
}

extern "C" void kernel_launch(void* const* d_in, const int* in_sizes, int n_in,
                              void* d_out, int out_size, void* d_ws, size_t ws_size,
                              hipStream_t stream) {
    const float* x     = (const float*)d_in[0];
    const float* cw    = (const float*)d_in[1];
    const float* bn_w  = (const float*)d_in[2];
    const float* bn_b  = (const float*)d_in[3];
    const float* bn_m  = (const float*)d_in[4];
    const float* bn_v  = (const float*)d_in[5];
    const float* gamma = (const float*)d_in[6];
    const float* beta  = (const float*)d_in[7];
    float* out = (float*)d_out;

    float* g = (float*)d_ws;                    // NB*NC floats
    float* f = g + NB * NC;                     // NB*KC floats

    gap_kernel<<<NB * NC, 256, 0, stream>>>(x, g);
    filt_kernel<<<dim3(24, NB), 256, 0, stream>>>(g, cw, bn_w, bn_b, bn_m, bn_v, f);
    apply_kernel<<<NB * (NC / CG) * 2, 256, 0, stream>>>(x, f, gamma, beta, out);
}